// Round 8
// baseline (279.687 us; speedup 1.0000x reference)
//
#include <hip/hip_runtime.h>
#include <hip/hip_bf16.h>

#define D 128
typedef _Float16 f16;
typedef f16 f16x8 __attribute__((ext_vector_type(8)));
typedef f16 f16x4 __attribute__((ext_vector_type(4)));
typedef f16 f16x2 __attribute__((ext_vector_type(2)));
typedef float f32x4 __attribute__((ext_vector_type(4)));

// Feature permutation: storage pos = (col&15)*8 + (col>>4); col = 16*(pos&7) + (pos>>3).
// H/act rows are stored permuted (MFMA-native) so the GEMM epilogue is contiguous
// f16x8 stores. Layers 1-2 contract over permuted k using row-permuted WT.
// Bias is pre-permuted into bperm so agg reads it coalesced.

// ---------------- CSR build (+ W/bias convert piggybacked) ----------------

__global__ void hist_cvt_kernel(const int* __restrict__ col, int* __restrict__ cnt, int E,
                                const float* __restrict__ W0, const float* __restrict__ W1,
                                const float* __restrict__ W2,
                                const float* __restrict__ b0, const float* __restrict__ b1,
                                const float* __restrict__ b2,
                                f16* __restrict__ WT, float* __restrict__ bperm) {
    const int EB = (E + 255) >> 8;
    const int b = blockIdx.x;
    if (b < EB) {
        int i = b * 256 + threadIdx.x;
        if (i < E) atomicAdd(&cnt[col[i]], 1);
    } else {
        int id = (b - EB) * 256 + threadIdx.x;
        if (id < 49152) {                            // 3*16384 W entries
            int l = id >> 14;
            int e = id & 16383;
            int j = e >> 7;                          // storage k index (pos)
            int nn = e & 127;
            int k = (l == 0) ? j : ((j >> 3) + 16 * (j & 7));   // orig k
            const float* W = (l == 0) ? W0 : (l == 1) ? W1 : W2;
            WT[(size_t)l * 16384 + nn * 128 + j] = (f16)W[k * 128 + nn];
        } else if (id < 49536) {                     // 3*128 bias entries
            int j = id - 49152;
            int l = j >> 7;
            int pos = j & 127;
            int c = 16 * (pos & 7) + (pos >> 3);     // orig col
            const float* bb = (l == 0) ? b0 : (l == 1) ? b1 : b2;
            bperm[l * 128 + pos] = bb[c];
        }
    }
}

__global__ __launch_bounds__(256) void scan_part1(const int* __restrict__ cnt,
                                                  int* __restrict__ bsum, int n) {
    __shared__ int ws[4];
    const int tid = threadIdx.x;
    const int i = blockIdx.x * 256 + tid;
    int v = (i < n) ? cnt[i] : 0;
    #pragma unroll
    for (int off = 32; off > 0; off >>= 1) v += __shfl_down(v, off, 64);
    if ((tid & 63) == 0) ws[tid >> 6] = v;
    __syncthreads();
    if (tid == 0) bsum[blockIdx.x] = ws[0] + ws[1] + ws[2] + ws[3];
}

__global__ __launch_bounds__(256) void scan_part2(const int* __restrict__ bsum,
                                                  int* __restrict__ bpre,
                                                  int* __restrict__ total_out, int nb) {
    __shared__ int ws[4];
    const int tid = threadIdx.x;
    const int lane = tid & 63;
    const int wid = tid >> 6;
    int v = (tid < nb) ? bsum[tid] : 0;
    int x = v;
    #pragma unroll
    for (int off = 1; off < 64; off <<= 1) {
        int y = __shfl_up(x, off, 64);
        if (lane >= off) x += y;
    }
    if (lane == 63) ws[wid] = x;
    __syncthreads();
    int wpre = 0;
    #pragma unroll
    for (int w = 0; w < 4; ++w) if (w < wid) wpre += ws[w];
    int inc = wpre + x;
    if (tid < nb) bpre[tid] = inc - v;
    if (tid == 255) *total_out = inc;
}

// scan finalize + dis computation fused
__global__ __launch_bounds__(256) void scan_part3(const int* __restrict__ cnt,
                                                  const int* __restrict__ bpre,
                                                  int* __restrict__ ptr,
                                                  float* __restrict__ dis,
                                                  int n, int n_pad) {
    __shared__ int ws[4];
    const int tid = threadIdx.x;
    const int lane = tid & 63;
    const int wid = tid >> 6;
    const int i = blockIdx.x * 256 + tid;
    int v = (i < n) ? cnt[i] : 0;
    int x = v;
    #pragma unroll
    for (int off = 1; off < 64; off <<= 1) {
        int y = __shfl_up(x, off, 64);
        if (lane >= off) x += y;
    }
    if (lane == 63) ws[wid] = x;
    __syncthreads();
    int wpre = 0;
    #pragma unroll
    for (int w = 0; w < 4; ++w) if (w < wid) wpre += ws[w];
    if (i < n) ptr[i] = bpre[blockIdx.x] + wpre + x - v;
    if (i < n_pad) dis[i] = (i < n) ? rsqrtf((float)(v + 1)) : 0.f;
}

__global__ void scatter_kernel(const int* __restrict__ row, const int* __restrict__ col,
                               const int* __restrict__ ptr, int* __restrict__ fill,
                               int* __restrict__ ssrc, int E) {
    int i = blockIdx.x * 256 + threadIdx.x;
    if (i < E) {
        int d = col[i];
        int p = ptr[d] + atomicAdd(&fill[d], 1);
        ssrc[p] = row[i];
    }
}

// ---------------- MFMA fp16 GEMM: H[r][pos] = (f16)( dis[r] * (A @ W)[r][col(pos)] ) ----
// 64 rows/block (4 waves x 16 rows), K=N=128. W staged once into swizzled LDS;
// A fragments direct from global (issued before staging). Output stored in the
// permuted feature layout -> per-lane contiguous f16x8 stores (coalesced).

template <bool A_F32>
__global__ __launch_bounds__(256) void gemm_mfma(const void* __restrict__ Aptr,
                                                 const f16* __restrict__ WT,
                                                 const float* __restrict__ dis,
                                                 f16* __restrict__ H, int n) {
    __shared__ f16 sW[128 * 128];   // 32 KB
    const int tid  = threadIdx.x;
    const int w    = tid >> 6, lane = tid & 63;
    const int q    = lane >> 4, c = lane & 15;
    const int row0 = blockIdx.x * 64;

    int arow = row0 + w * 16 + c;
    if (arow >= n) arow = n - 1;          // clamp; epilogue guards stores

    // A fragments direct from global — issue before W staging
    f16x8 afr[4];
    if (A_F32) {
        float4 x0[4], x1[4];
        #pragma unroll
        for (int t = 0; t < 4; ++t) {
            const float* src = (const float*)Aptr + (size_t)arow * D + (t * 4 + q) * 8;
            x0[t] = *(const float4*)src;
            x1[t] = *(const float4*)(src + 4);
        }
        #pragma unroll
        for (int t = 0; t < 4; ++t) {
            f16x8 h;
            h[0] = (f16)x0[t].x; h[1] = (f16)x0[t].y; h[2] = (f16)x0[t].z; h[3] = (f16)x0[t].w;
            h[4] = (f16)x1[t].x; h[5] = (f16)x1[t].y; h[6] = (f16)x1[t].z; h[7] = (f16)x1[t].w;
            afr[t] = h;
        }
    } else {
        #pragma unroll
        for (int t = 0; t < 4; ++t)
            afr[t] = *(const f16x8*)((const f16*)Aptr + (size_t)arow * D + (t * 4 + q) * 8);
    }

    // stage W (2048 16B units, swizzled: unit (r,b) -> r*16 + (b^(r&15)))
    #pragma unroll
    for (int i = 0; i < 8; ++i) {
        int f = i * 256 + tid;
        int r = f >> 4, b = f & 15;
        int u = (r << 4) | (b ^ (r & 15));
        *(f16x8*)&sW[u * 8] = *(const f16x8*)&WT[(size_t)r * D + b * 8];
    }
    __syncthreads();

    f32x4 acc[8];
    #pragma unroll
    for (int nt = 0; nt < 8; ++nt) acc[nt] = (f32x4)0.f;

    #pragma unroll
    for (int nt = 0; nt < 8; ++nt) {
        const int rn = nt * 16 + c;
        #pragma unroll
        for (int t = 0; t < 4; ++t) {
            f16x8 bfr = *(const f16x8*)&sW[(((rn << 4) | ((t * 4 + q) ^ c))) * 8];
            acc[nt] = __builtin_amdgcn_mfma_f32_16x16x32_f16(afr[t], bfr, acc[nt], 0, 0, 0);
        }
    }

    // epilogue: lane holds cols {nt*16+c} for rows q*4+reg -> permuted pos = c*8+nt
    const int rbase = row0 + w * 16 + q * 4;
    float4 dv4 = *(const float4*)&dis[rbase];     // dis zero-padded to n_pad
    #pragma unroll
    for (int reg = 0; reg < 4; ++reg) {
        int grow = rbase + reg;
        if (grow < n) {
            float dv = (reg == 0) ? dv4.x : (reg == 1) ? dv4.y : (reg == 2) ? dv4.z : dv4.w;
            f16x8 hh;
            #pragma unroll
            for (int nt = 0; nt < 8; ++nt) hh[nt] = (f16)(acc[nt][reg] * dv);
            *(f16x8*)&H[(size_t)grow * D + c * 8] = hh;
        }
    }
}

// ---------------- Aggregation: 1 node/wave, 4 rows per gather instruction ----------------
// 16 lanes x f16x8 (16B) per row; slot = lane>>4 in {0..3} processes edges e+slot.
// Cross-slot fold via shfl_xor(16), shfl_xor(32) at the end.
// H pre-scaled by dis[src]:  y[v][pos] = relu( dis[v]*(H[v]+sum H[src])[pos] + bperm[pos] )

template <bool LAST>
__global__ __launch_bounds__(256) void agg_kernel(const f16* __restrict__ H,
                                                  const int* __restrict__ ptr,
                                                  const int* __restrict__ ssrc,
                                                  const float* __restrict__ dis,
                                                  const float* __restrict__ bperm,
                                                  float* __restrict__ out,
                                                  f16* __restrict__ act, int n) {
    const int v    = (blockIdx.x * 256 + threadIdx.x) >> 6;
    const int lane = threadIdx.x & 63;
    if (v >= n) return;
    const int slot = lane >> 4;          // 0..3
    const int fl   = lane & 15;          // feature-slice lane
    const int fo   = fl * 8;             // f16 offset (16 B) within row

    float a[8];
    if (slot == 0) {                     // self-loop once
        f16x8 hv = *(const f16x8*)&H[(size_t)v * D + fo];
        #pragma unroll
        for (int j = 0; j < 8; ++j) a[j] = (float)hv[j];
    } else {
        #pragma unroll
        for (int j = 0; j < 8; ++j) a[j] = 0.f;
    }

    int e = ptr[v];
    const int e1 = ptr[v + 1];
    for (; e + 8 <= e1; e += 8) {        // 8 edges: 2 gathers/lane in flight
        int s0 = ssrc[e + slot];
        int s1 = ssrc[e + 4 + slot];
        f16x8 h0 = *(const f16x8*)&H[(size_t)s0 * D + fo];
        f16x8 h1 = *(const f16x8*)&H[(size_t)s1 * D + fo];
        #pragma unroll
        for (int j = 0; j < 8; ++j) a[j] += (float)h0[j] + (float)h1[j];
    }
    for (; e + 4 <= e1; e += 4) {        // 4 edges
        int s0 = ssrc[e + slot];
        f16x8 h0 = *(const f16x8*)&H[(size_t)s0 * D + fo];
        #pragma unroll
        for (int j = 0; j < 8; ++j) a[j] += (float)h0[j];
    }
    if (e + slot < e1) {                 // tail (<4), slot-predicated
        int s0 = ssrc[e + slot];
        f16x8 h0 = *(const f16x8*)&H[(size_t)s0 * D + fo];
        #pragma unroll
        for (int j = 0; j < 8; ++j) a[j] += (float)h0[j];
    }

    // fold the 4 slots (lane bits 4,5)
    #pragma unroll
    for (int j = 0; j < 8; ++j) {
        a[j] += __shfl_xor(a[j], 16, 64);
        a[j] += __shfl_xor(a[j], 32, 64);
    }

    const float dv = dis[v];
    // each lane finalizes its slot's feature pair: pos = fo + 2*slot + {0,1}
    const int jp = 2 * slot;
    float2 bb = *(const float2*)&bperm[fo + jp];
    float r0 = fmaxf(fmaf(dv, a[jp],     bb.x), 0.f);
    float r1 = fmaxf(fmaf(dv, a[jp + 1], bb.y), 0.f);
    if (LAST) {
        // un-permute: pos p = fo+jp+t -> orig col = 16*((jp+t)&7) + fl
        out[(size_t)v * D + 16 * (jp & 7)       + fl] = r0;
        out[(size_t)v * D + 16 * ((jp + 1) & 7) + fl] = r1;
    } else {
        f16x2 res;
        res[0] = (f16)r0; res[1] = (f16)r1;
        *(f16x2*)&act[(size_t)v * D + fo + jp] = res;   // 64 lanes cover the 256B row
    }
}

// ---------------- launch ----------------

extern "C" void kernel_launch(void* const* d_in, const int* in_sizes, int n_in,
                              void* d_out, int out_size, void* d_ws, size_t ws_size,
                              hipStream_t stream) {
    const float* x  = (const float*)d_in[0];
    const int*   ei = (const int*)d_in[1];
    const float* W0 = (const float*)d_in[2];
    const float* b0 = (const float*)d_in[3];
    const float* W1 = (const float*)d_in[4];
    const float* b1 = (const float*)d_in[5];
    const float* W2 = (const float*)d_in[6];
    const float* b2 = (const float*)d_in[7];
    float* out = (float*)d_out;

    const int n = in_sizes[0] / D;          // 50000
    const int E = in_sizes[1] / 2;          // 640000
    const int n_pad = (n + 63) & ~63;       // 50048
    const int* row = ei;
    const int* col = ei + E;
    const int nb = (n + 255) / 256;
    const int EB = (E + 255) / 256;

    char* w = (char*)d_ws;
    size_t o = 0;
    f16* hbuf = (f16*)(w + o); o += (size_t)n_pad * D * 2;
    f16* act  = (f16*)(w + o); o += (size_t)n_pad * D * 2;
    f16* WT   = (f16*)(w + o); o += (size_t)3 * 16384 * 2;
    o = (o + 63) & ~(size_t)63;
    float* bperm = (float*)(w + o); o += 3 * 128 * 4;
    int* cnt  = (int*)(w + o); o += (size_t)n * 4;
    int* fill = (int*)(w + o); o += (size_t)n * 4;   // adjacent to cnt -> one memset
    int* ptrv = (int*)(w + o); o += (size_t)(n + 1) * 4;
    o = (o + 63) & ~(size_t)63;
    float* dis = (float*)(w + o); o += (size_t)n_pad * 4;
    int* bsum = (int*)(w + o); o += 256 * 4;
    int* bpre = (int*)(w + o); o += 256 * 4;
    o = (o + 63) & ~(size_t)63;
    int* ssrc = (int*)(w + o);

    // CSR build (graph identical across layers); W/bias convert piggybacked
    hipMemsetAsync(cnt, 0, (size_t)n * 8, stream);
    hist_cvt_kernel<<<EB + 194, 256, 0, stream>>>(col, cnt, E, W0, W1, W2,
                                                  b0, b1, b2, WT, bperm);
    scan_part1<<<nb, 256, 0, stream>>>(cnt, bsum, n);
    scan_part2<<<1, 256, 0, stream>>>(bsum, bpre, ptrv + n, nb);
    scan_part3<<<nb, 256, 0, stream>>>(cnt, bpre, ptrv, dis, n, n_pad);
    scatter_kernel<<<EB, 256, 0, stream>>>(row, col, ptrv, fill, ssrc, E);

    const int gblocks = (n + 63) / 64;
    const int ablocks = (n + 3) / 4;         // 1 node/wave, 4 waves/block

    // layer 0: A = x (fp32, natural k) with natural-k WT0
    gemm_mfma<true><<<gblocks, 256, 0, stream>>>(x, WT, dis, hbuf, n);
    agg_kernel<false><<<ablocks, 256, 0, stream>>>(hbuf, ptrv, ssrc, dis, bperm, out, act, n);
    // layer 1 (perm-k A, perm-k WT)
    gemm_mfma<false><<<gblocks, 256, 0, stream>>>(act, WT + 16384, dis, hbuf, n);
    agg_kernel<false><<<ablocks, 256, 0, stream>>>(hbuf, ptrv, ssrc, dis, bperm + 128, out, act, n);
    // layer 2 -> fp32 d_out (un-permuted stores)
    gemm_mfma<false><<<gblocks, 256, 0, stream>>>(act, WT + 2 * 16384, dis, hbuf, n);
    agg_kernel<true><<<ablocks, 256, 0, stream>>>(hbuf, ptrv, ssrc, dis, bperm + 256, out, act, n);
}